// Round 1
// baseline (150.197 us; speedup 1.0000x reference)
//
#include <hip/hip_runtime.h>

#define BATCH 512
#define EMBED 512
#define BLOCK 256

__global__ __launch_bounds__(BLOCK) void fused_margin_loss(
    const float* __restrict__ X,
    const int* __restrict__ labels,
    const float* __restrict__ mu,
    const float* __restrict__ nv,
    float* __restrict__ out,
    int n_classes)
{
    __shared__ float xi[EMBED];
    __shared__ float drow[BATCH];
    __shared__ int   lab[BATCH];
    __shared__ float red[BLOCK / 64];

    const int i = blockIdx.x;
    const int tid = threadIdx.x;

    // stage labels and x_i into LDS
    for (int t = tid; t < BATCH; t += BLOCK) lab[t] = labels[t];
    const float4* Xi4 = (const float4*)(X + (size_t)i * EMBED);
    for (int t = tid; t < EMBED / 4; t += BLOCK) ((float4*)xi)[t] = Xi4[t];
    __syncthreads();

    // D row i: drow[j] = dot(x_i, X[j])  (X fits in L2; per-thread row dot)
    for (int j = tid; j < BATCH; j += BLOCK) {
        const float4* Xj = (const float4*)(X + (size_t)j * EMBED);
        float a0 = 0.f, a1 = 0.f, a2 = 0.f, a3 = 0.f;
#pragma unroll 8
        for (int c = 0; c < EMBED / 4; ++c) {
            float4 a = ((const float4*)xi)[c];
            float4 b = Xj[c];
            a0 = fmaf(a.x, b.x, a0);
            a1 = fmaf(a.y, b.y, a1);
            a2 = fmaf(a.z, b.z, a2);
            a3 = fmaf(a.w, b.w, a3);
        }
        drow[j] = (a0 + a1) + (a2 + a3);
    }
    __syncthreads();

    const int li = lab[i];
    const float mu_i = mu[li];

    // hinge: sum over pos j (same label, j!=i), neg k (diff label)
    float local = 0.0f;
    for (int j = 0; j < BATCH; ++j) {
        if (j == i || lab[j] != li) continue;  // wave-uniform branch
        const float dij_mu = drow[j] + mu_i;
#pragma unroll
        for (int kk = 0; kk < BATCH / BLOCK; ++kk) {
            int k = tid + kk * BLOCK;
            if (lab[k] != li) {
                float t = dij_mu - drow[k];
                local += fmaxf(t, 0.0f);
            }
        }
    }

    // regularizer: block 0 folds in -(sum(mu)+sum(nv))/C
    if (i == 0 && tid < n_classes) {
        local -= (mu[tid] + nv[tid]) / (float)n_classes;
    }

    // block reduction: wave shuffle then LDS
    for (int off = 32; off > 0; off >>= 1)
        local += __shfl_down(local, off, 64);
    const int wave = tid >> 6;
    const int lane = tid & 63;
    if (lane == 0) red[wave] = local;
    __syncthreads();
    if (tid == 0) {
        float s = 0.f;
        for (int w = 0; w < BLOCK / 64; ++w) s += red[w];
        atomicAdd(out, s);
    }
}

extern "C" void kernel_launch(void* const* d_in, const int* in_sizes, int n_in,
                              void* d_out, int out_size, void* d_ws, size_t ws_size,
                              hipStream_t stream) {
    const float* X      = (const float*)d_in[0];
    const int*   labels = (const int*)d_in[1];
    const float* mu     = (const float*)d_in[2];
    const float* nv     = (const float*)d_in[3];
    float* out = (float*)d_out;
    const int n_classes = in_sizes[2];

    // d_out is poisoned before every launch — zero it (memset nodes are graph-capturable)
    hipMemsetAsync(out, 0, sizeof(float), stream);

    fused_margin_loss<<<dim3(BATCH), dim3(BLOCK), 0, stream>>>(
        X, labels, mu, nv, out, n_classes);
}

// Round 2
// 113.048 us; speedup vs baseline: 1.3286x; 1.3286x over previous
//
#include <hip/hip_runtime.h>

#define BATCH 512
#define EMBED 512
#define BLOCK 256
#define TS 32   // gram tile size

// ---------------- Kernel 1: D = X * X^T (fp32, tiled) ----------------
__global__ __launch_bounds__(256) void gram_gemm(
    const float* __restrict__ X, float* __restrict__ D)
{
    // +4 pad keeps 16B alignment for float4 LDS stores and breaks pow2 stride
    __shared__ float As[TS][TS + 4];
    __shared__ float Bs[TS][TS + 4];

    const int tid  = threadIdx.x;
    const int row0 = blockIdx.y * TS;
    const int col0 = blockIdx.x * TS;

    // load mapping: 256 threads load 32x32 floats as float4 each
    const int lr = tid >> 3;          // 0..31 row within tile
    const int lc = (tid & 7) << 2;    // 0,4,...,28 col within tile

    // compute mapping: 16x16 threads, 2x2 outputs each
    const int ty = tid >> 4;          // 0..15
    const int tx = tid & 15;          // 0..15

    float acc00 = 0.f, acc01 = 0.f, acc10 = 0.f, acc11 = 0.f;

    for (int kc = 0; kc < EMBED; kc += TS) {
        float4 a = *(const float4*)(X + (size_t)(row0 + lr) * EMBED + kc + lc);
        float4 b = *(const float4*)(X + (size_t)(col0 + lr) * EMBED + kc + lc);
        *(float4*)&As[lr][lc] = a;
        *(float4*)&Bs[lr][lc] = b;
        __syncthreads();

#pragma unroll
        for (int kk = 0; kk < TS; ++kk) {
            float a0 = As[ty][kk];
            float a1 = As[ty + 16][kk];
            float b0 = Bs[tx][kk];
            float b1 = Bs[tx + 16][kk];
            acc00 = fmaf(a0, b0, acc00);
            acc01 = fmaf(a0, b1, acc01);
            acc10 = fmaf(a1, b0, acc10);
            acc11 = fmaf(a1, b1, acc11);
        }
        __syncthreads();
    }

    float* Dp = D + (size_t)(row0 + ty) * BATCH + col0 + tx;
    Dp[0]  = acc00;
    Dp[16] = acc01;
    Dp += (size_t)16 * BATCH;
    Dp[0]  = acc10;
    Dp[16] = acc11;
}

// ---------------- Kernel 2: hinge reduction over (pos j, neg k) ----------------
__global__ __launch_bounds__(BLOCK) void hinge_reduce(
    const float* __restrict__ D,
    const int* __restrict__ labels,
    const float* __restrict__ mu,
    const float* __restrict__ nv,
    float* __restrict__ out,
    int n_classes)
{
    __shared__ float drow[BATCH];
    __shared__ int   lab[BATCH];
    __shared__ float red[BLOCK / 64];

    const int i = blockIdx.x;
    const int tid = threadIdx.x;

    for (int t = tid; t < BATCH; t += BLOCK) lab[t] = labels[t];
    // coalesced row load: 128 float4
    if (tid < BATCH / 4)
        ((float4*)drow)[tid] = ((const float4*)(D + (size_t)i * BATCH))[tid];
    __syncthreads();

    const int li = lab[i];
    const float mu_i = mu[li];

    float local = 0.0f;
    for (int j = 0; j < BATCH; ++j) {
        if (j == i || lab[j] != li) continue;  // wave-uniform skip
        const float dij_mu = drow[j] + mu_i;
#pragma unroll
        for (int kk = 0; kk < BATCH / BLOCK; ++kk) {
            int k = tid + kk * BLOCK;
            if (lab[k] != li) {
                float t = dij_mu - drow[k];
                local += fmaxf(t, 0.0f);
            }
        }
    }

    if (i == 0 && tid < n_classes)
        local -= (mu[tid] + nv[tid]) / (float)n_classes;

    for (int off = 32; off > 0; off >>= 1)
        local += __shfl_down(local, off, 64);
    const int wave = tid >> 6;
    const int lane = tid & 63;
    if (lane == 0) red[wave] = local;
    __syncthreads();
    if (tid == 0) {
        float s = 0.f;
        for (int w = 0; w < BLOCK / 64; ++w) s += red[w];
        atomicAdd(out, s);
    }
}

extern "C" void kernel_launch(void* const* d_in, const int* in_sizes, int n_in,
                              void* d_out, int out_size, void* d_ws, size_t ws_size,
                              hipStream_t stream) {
    const float* X      = (const float*)d_in[0];
    const int*   labels = (const int*)d_in[1];
    const float* mu     = (const float*)d_in[2];
    const float* nv     = (const float*)d_in[3];
    float* out = (float*)d_out;
    float* D   = (float*)d_ws;   // 512*512*4 = 1 MB
    const int n_classes = in_sizes[2];

    hipMemsetAsync(out, 0, sizeof(float), stream);

    dim3 ggrid(BATCH / TS, BATCH / TS);  // 16x16 = 256 blocks
    gram_gemm<<<ggrid, dim3(256), 0, stream>>>(X, D);

    hinge_reduce<<<dim3(BATCH), dim3(BLOCK), 0, stream>>>(
        D, labels, mu, nv, out, n_classes);
}

// Round 3
// 79.769 us; speedup vs baseline: 1.8829x; 1.4172x over previous
//
#include <hip/hip_runtime.h>

#define BATCH 512
#define EMBED 512
#define BLOCK 256
#define TS 32        // gram tile size
#define KSPLIT 2     // split-K slabs

// ---------------- Kernel 1: partial Gram slabs  Dp[z] = X[:, zK:(z+1)K] * X[:, zK:(z+1)K]^T ----------------
__global__ __launch_bounds__(256) void gram_gemm(
    const float* __restrict__ X, float* __restrict__ Dp)
{
    __shared__ float As[TS][TS + 4];   // +4 keeps float4 alignment (144B rows)
    __shared__ float Bs[TS][TS + 4];

    const int tid   = threadIdx.x;
    const int row0  = blockIdx.y * TS;
    const int col0  = blockIdx.x * TS;
    const int kbase = blockIdx.z * (EMBED / KSPLIT);

    // staging: 256 threads load 32x32 floats as float4
    const int lr = tid >> 3;
    const int lc = (tid & 7) << 2;
    // compute: 16x16 threads, 2x2 outputs
    const int ty = tid >> 4;
    const int tx = tid & 15;

    float acc00 = 0.f, acc01 = 0.f, acc10 = 0.f, acc11 = 0.f;

    for (int kc = kbase; kc < kbase + EMBED / KSPLIT; kc += TS) {
        *(float4*)&As[lr][lc] = *(const float4*)(X + (size_t)(row0 + lr) * EMBED + kc + lc);
        *(float4*)&Bs[lr][lc] = *(const float4*)(X + (size_t)(col0 + lr) * EMBED + kc + lc);
        __syncthreads();

#pragma unroll
        for (int kk = 0; kk < TS; kk += 4) {
            float4 a0 = *(float4*)&As[ty][kk];
            float4 a1 = *(float4*)&As[ty + 16][kk];
            float4 b0 = *(float4*)&Bs[tx][kk];
            float4 b1 = *(float4*)&Bs[tx + 16][kk];
            acc00 = fmaf(a0.x, b0.x, acc00); acc00 = fmaf(a0.y, b0.y, acc00);
            acc00 = fmaf(a0.z, b0.z, acc00); acc00 = fmaf(a0.w, b0.w, acc00);
            acc01 = fmaf(a0.x, b1.x, acc01); acc01 = fmaf(a0.y, b1.y, acc01);
            acc01 = fmaf(a0.z, b1.z, acc01); acc01 = fmaf(a0.w, b1.w, acc01);
            acc10 = fmaf(a1.x, b0.x, acc10); acc10 = fmaf(a1.y, b0.y, acc10);
            acc10 = fmaf(a1.z, b0.z, acc10); acc10 = fmaf(a1.w, b0.w, acc10);
            acc11 = fmaf(a1.x, b1.x, acc11); acc11 = fmaf(a1.y, b1.y, acc11);
            acc11 = fmaf(a1.z, b1.z, acc11); acc11 = fmaf(a1.w, b1.w, acc11);
        }
        __syncthreads();
    }

    float* O = Dp + (size_t)blockIdx.z * BATCH * BATCH
                  + (size_t)(row0 + ty) * BATCH + col0 + tx;
    O[0]  = acc00;
    O[16] = acc01;
    O += (size_t)16 * BATCH;
    O[0]  = acc00 * 0.f + acc10;  // plain stores
    O[16] = acc11;
}

// ---------------- Kernel 2: hinge reduction with compacted positive list ----------------
__global__ __launch_bounds__(BLOCK) void hinge_reduce(
    const float* __restrict__ Dp,
    const int* __restrict__ labels,
    const float* __restrict__ mu,
    const float* __restrict__ nv,
    float* __restrict__ out,
    int n_classes)
{
    __shared__ float drow[BATCH];
    __shared__ int   lab[BATCH];
    __shared__ int   poslist[BATCH];
    __shared__ float dijmu[BATCH];
    __shared__ int   npos_s;
    __shared__ float red[BLOCK / 64];

    const int i = blockIdx.x;
    const int tid = threadIdx.x;

    if (tid == 0) npos_s = 0;
    for (int t = tid; t < BATCH; t += BLOCK) lab[t] = labels[t];
    if (tid < BATCH / 4) {
        float4 d0 = ((const float4*)(Dp + (size_t)i * BATCH))[tid];
        float4 d1 = ((const float4*)(Dp + (size_t)BATCH * BATCH + (size_t)i * BATCH))[tid];
        float4 s; s.x = d0.x + d1.x; s.y = d0.y + d1.y; s.z = d0.z + d1.z; s.w = d0.w + d1.w;
        ((float4*)drow)[tid] = s;
    }
    __syncthreads();

    const int li = lab[i];
    const float mu_i = mu[li];

    // compact positives j (same label, j != i)
    for (int t = tid; t < BATCH; t += BLOCK) {
        if (t != i && lab[t] == li) {
            int idx = atomicAdd(&npos_s, 1);
            poslist[idx] = t;
        }
    }
    __syncthreads();
    const int npos = npos_s;
    for (int t = tid; t < npos; t += BLOCK)
        dijmu[t] = drow[poslist[t]] + mu_i;
    __syncthreads();

    float local = 0.0f;
#pragma unroll
    for (int kk = 0; kk < BATCH / BLOCK; ++kk) {
        int k = tid + kk * BLOCK;
        if (lab[k] != li) {                 // k is a valid negative
            float dk = drow[k];
            for (int p = 0; p < npos; ++p)
                local += fmaxf(dijmu[p] - dk, 0.0f);
        }
    }

    if (i == 0 && tid < n_classes)
        local -= (mu[tid] + nv[tid]) / (float)n_classes;

    for (int off = 32; off > 0; off >>= 1)
        local += __shfl_down(local, off, 64);
    const int wave = tid >> 6;
    const int lane = tid & 63;
    if (lane == 0) red[wave] = local;
    __syncthreads();
    if (tid == 0) {
        float s = 0.f;
        for (int w = 0; w < BLOCK / 64; ++w) s += red[w];
        atomicAdd(out, s);
    }
}

extern "C" void kernel_launch(void* const* d_in, const int* in_sizes, int n_in,
                              void* d_out, int out_size, void* d_ws, size_t ws_size,
                              hipStream_t stream) {
    const float* X      = (const float*)d_in[0];
    const int*   labels = (const int*)d_in[1];
    const float* mu     = (const float*)d_in[2];
    const float* nv     = (const float*)d_in[3];
    float* out = (float*)d_out;
    float* Dp  = (float*)d_ws;   // 2 slabs * 1 MB
    const int n_classes = in_sizes[2];

    hipMemsetAsync(out, 0, sizeof(float), stream);

    dim3 ggrid(BATCH / TS, BATCH / TS, KSPLIT);  // 16x16x2 = 512 blocks
    gram_gemm<<<ggrid, dim3(256), 0, stream>>>(X, Dp);

    hinge_reduce<<<dim3(BATCH), dim3(BLOCK), 0, stream>>>(
        Dp, labels, mu, nv, out, n_classes);
}